// Round 13
// baseline (5637.294 us; speedup 1.0000x reference)
//
#include <hip/hip_runtime.h>
#include <hip/hip_bf16.h>

#define TT 3650
#define HH 256

typedef _Float16 f16x4 __attribute__((ext_vector_type(4)));
typedef _Float16 f16x8 __attribute__((ext_vector_type(8)));
typedef float f32x4 __attribute__((ext_vector_type(4)));

__device__ __forceinline__ float xexp2(float x) { return __builtin_amdgcn_exp2f(x); }
__device__ __forceinline__ float xrcp(float x) { return __builtin_amdgcn_rcpf(x); }
__device__ __forceinline__ float xexp(float x) { return xexp2(x * 1.4426950408889634f); }
__device__ __forceinline__ float xtanh(float x) {
  float e = xexp2(x * 2.8853900817779268f);  // e^{2x}
  return 1.0f - 2.0f * xrcp(e + 1.0f);
}
__device__ __forceinline__ float xstep(float x) {  // sigmoid(10x)
  return xrcp(1.0f + xexp2(-14.426950408889634f * x));
}
__device__ __forceinline__ float xsinh(float x) {
  float e = xexp(x);
  return 0.5f * (e - xrcp(e));
}

#define DPPADD(x, ctrl)                                                        \
  (x) += __builtin_bit_cast(float, __builtin_amdgcn_update_dpp(                \
            0, __builtin_bit_cast(int, (x)), (ctrl), 0xf, 0xf, false));
#define RDLANE(x, l)                                                           \
  __builtin_bit_cast(float,                                                    \
      __builtin_amdgcn_readlane(__builtin_bit_cast(int, (x)), (l)))

#define REP8(M) M(0) M(1) M(2) M(3) M(4) M(5) M(6) M(7)
#define REPC(M) M(0) M(1) M(2) M(3)

// Weights stored as fp16 of (W * 2^10): avoids fp16-denormal weights, which
// the MFMA pipe flushes (round-9 drift). Descale folded into the post-MFMA FMA.
#define WSCALE 1024.0f
#define WDESCALE 0.0009765625f

#define SF_PAD 1500

__global__ void __launch_bounds__(256, 1) exphydro_scan(
    const float* __restrict__ gin, const float* __restrict__ gdayl,
    const float* __restrict__ gW0, const float* __restrict__ gb0,
    const float* __restrict__ gW1, const float* __restrict__ gb1,
    const float* __restrict__ gW2, const float* __restrict__ gb2,
    const float* __restrict__ gWout, const float* __restrict__ gbout,
    float* __restrict__ gout) {
  __shared__ alignas(16) _Float16 h0l[HH];   // 512 B activation buffers
  __shared__ alignas(16) _Float16 h1l[HH];
  __shared__ float sWP[64];                  // [m][w]: slot m*4+w, 20 used
  __shared__ f32x4 sF[TT + SF_PAD];          // packed forcings {p,tm,ld,0} + pad

  const int tid = threadIdx.x;
  const int lane = tid & 63;
  const int w = tid >> 6;          // wave 0..3
  const int li = lane & 15;        // MFMA col within tile
  const int g = lane >> 4;         // k-group 0..3
  const int jb = 64 * w + 4 * li;  // this lane's 4 consecutive j's: jb+0..3

  // ---- stage packed forcings ----
  for (int i = tid; i < TT; i += 256) {
    f32x4 F = {gin[5 * i + 2], gin[5 * i + 3], gdayl[i], 0.0f};
    sF[i] = F;
  }
  if (tid < 64) sWP[tid] = 0.0f;   // slots >=20 stay 0 forever

  // ---- per-thread constants (j = jb + c, c = 0..3) ----
  float s0 = gin[0], s1 = gin[1];
  const float bo0 = gbout[0], bo1 = gbout[1], bo2 = gbout[2], bo3 = gbout[3],
              bo4 = gbout[4];
#define CDECL(c)                                                               \
  const float w00_##c = gW0[jb + (c)], w01_##c = gW0[HH + jb + (c)],           \
              w02_##c = gW0[2 * HH + jb + (c)],                                \
              w03_##c = gW0[3 * HH + jb + (c)], b0_##c = gb0[jb + (c)],        \
              b1_##c = gb1[jb + (c)], b2_##c = gb2[jb + (c)],                  \
              wo0_##c = gWout[5 * (jb + (c)) + 0],                             \
              wo1_##c = gWout[5 * (jb + (c)) + 1],                             \
              wo2_##c = gWout[5 * (jb + (c)) + 2],                             \
              wo3_##c = gWout[5 * (jb + (c)) + 3],                             \
              wo4_##c = gWout[5 * (jb + (c)) + 4];
  REPC(CDECL)
#undef CDECL

  // ---- weight B-fragments -> AGPRs (native MFMA operands, r10-proven).
  // Fragment (layer L, chain c, slice i): lane holds B[k][col=li] with
  // k = 32i + 8g + e, column j = jb + c.
#define FDECL(i) f16x8 a1_0_##i, a1_1_##i, a1_2_##i, a1_3_##i,                 \
                       a2_0_##i, a2_1_##i, a2_2_##i, a2_3_##i;
  REP8(FDECL)
#undef FDECL
#define MK(dst, G, i, c)                                                       \
  {                                                                            \
    const float* p = (G) + (32 * (i) + g * 8) * HH + jb + (c);                 \
    f16x8 f;                                                                   \
    f[0] = (_Float16)(p[0] * WSCALE);      f[1] = (_Float16)(p[HH] * WSCALE);  \
    f[2] = (_Float16)(p[2 * HH] * WSCALE); f[3] = (_Float16)(p[3 * HH] * WSCALE); \
    f[4] = (_Float16)(p[4 * HH] * WSCALE); f[5] = (_Float16)(p[5 * HH] * WSCALE); \
    f[6] = (_Float16)(p[6 * HH] * WSCALE); f[7] = (_Float16)(p[7 * HH] * WSCALE); \
    dst = f;                                                                   \
    asm volatile("" : "+a"(dst));                                              \
  }
#define FINIT(i)                                                               \
  MK(a1_0_##i, gW1, i, 0) MK(a1_1_##i, gW1, i, 1)                              \
  MK(a1_2_##i, gW1, i, 2) MK(a1_3_##i, gW1, i, 3)                              \
  MK(a2_0_##i, gW2, i, 0) MK(a2_1_##i, gW2, i, 1)                              \
  MK(a2_2_##i, gW2, i, 2) MK(a2_3_##i, gW2, i, 3)
  REP8(FINIT)
#undef FINIT
#undef MK

  const char* hp0 = (const char*)h0l + g * 16;  // A-fill base (k-group window)
  const char* hp1 = (const char*)h1l + g * 16;

  // VOLATILE MFMA: volatile asms cannot be reordered against each other, so
  // the round-robin chain interleave below is pinned in the emitted code.
  // (r12 evidence: non-volatile MFMAs got regrouped per-accumulator by the
  // scheduler -> 15 cyc/MFMA dependent-latency instead of ~5 cyc issue.)
#define MFMAV(acc, a, b)                                                       \
  asm volatile("v_mfma_f32_16x16x32_f16 %0, %1, %2, %0"                        \
               : "+v"(acc) : "v"(a), "a"(b));
// 4 MFMAs, one per j-chain c=0..3, same A operand, sub-accumulator set `suf`
#define M4(suf, av, L, s)                                                      \
  MFMAV(d0##suf, av, a##L##_0_##s) MFMAV(d1##suf, av, a##L##_1_##s)            \
  MFMAV(d2##suf, av, a##L##_2_##s) MFMAV(d3##suf, av, a##L##_3_##s)

  __syncthreads();  // staging + sWP zero visible

  f32x4 Fc = sF[0];
  for (int t = 0; t < TT; ++t) {
    const float p_in = Fc[0];
    const float tm = Fc[1];
    const float ld = Fc[2];

    // ---- layer 0 (VALU; each lane computes its 4 j's, g>0 redundant) ----
#define L0C(c)                                                                 \
  float h0_##c =                                                               \
      xtanh(b0_##c + s0 * w00_##c + s1 * w01_##c + p_in * w02_##c + tm * w03_##c);
    REPC(L0C)
#undef L0C
    if (lane < 16) {
      f16x4 hv = {(_Float16)h0_0, (_Float16)h0_1, (_Float16)h0_2,
                  (_Float16)h0_3};
      *(f16x4*)((char*)h0l + (jb << 1)) = hv;  // one ds_write_b64
    }
    __syncthreads();  // A

    f32x4 Fn = sF[t + 1];  // prefetch next forcings (SF_PAD covers t=TT-1)

    float h1_0, h1_1, h1_2, h1_3;
    {
      // ---- layer 1: 8 independent MFMA chains (4 j-chains x 2 slice-halves),
      // issued round-robin; dep distance = 8 instructions ----
      f16x8 av0 = *(const f16x8*)(hp0 + 0 * 64);
      f16x8 av1 = *(const f16x8*)(hp0 + 1 * 64);
      f16x8 av2 = *(const f16x8*)(hp0 + 2 * 64);
      f16x8 av3 = *(const f16x8*)(hp0 + 3 * 64);
      f16x8 av4 = *(const f16x8*)(hp0 + 4 * 64);
      f16x8 av5 = *(const f16x8*)(hp0 + 5 * 64);
      f16x8 av6 = *(const f16x8*)(hp0 + 6 * 64);
      f16x8 av7 = *(const f16x8*)(hp0 + 7 * 64);
      f32x4 d0a = {0.f, 0.f, 0.f, 0.f}, d1a = {0.f, 0.f, 0.f, 0.f};
      f32x4 d2a = {0.f, 0.f, 0.f, 0.f}, d3a = {0.f, 0.f, 0.f, 0.f};
      f32x4 d0b = {0.f, 0.f, 0.f, 0.f}, d1b = {0.f, 0.f, 0.f, 0.f};
      f32x4 d2b = {0.f, 0.f, 0.f, 0.f}, d3b = {0.f, 0.f, 0.f, 0.f};
      asm volatile("s_nop 1"
                   : "+v"(d0a), "+v"(d1a), "+v"(d2a), "+v"(d3a),
                     "+v"(d0b), "+v"(d1b), "+v"(d2b), "+v"(d3b));
      M4(a, av0, 1, 0) M4(b, av4, 1, 4)
      M4(a, av1, 1, 1) M4(b, av5, 1, 5)
      M4(a, av2, 1, 2) M4(b, av6, 1, 6)
      M4(a, av3, 1, 3) M4(b, av7, 1, 7)
      asm volatile("s_nop 7\n\ts_nop 7"
                   : "+v"(d0a), "+v"(d1a), "+v"(d2a), "+v"(d3a),
                     "+v"(d0b), "+v"(d1b), "+v"(d2b), "+v"(d3b));
      h1_0 = xtanh((d0a[0] + d0b[0]) * WDESCALE + b1_0);
      h1_1 = xtanh((d1a[0] + d1b[0]) * WDESCALE + b1_1);
      h1_2 = xtanh((d2a[0] + d2b[0]) * WDESCALE + b1_2);
      h1_3 = xtanh((d3a[0] + d3b[0]) * WDESCALE + b1_3);
    }
    if (lane < 16) {
      f16x4 hv = {(_Float16)h1_0, (_Float16)h1_1, (_Float16)h1_2,
                  (_Float16)h1_3};
      *(f16x4*)((char*)h1l + (jb << 1)) = hv;
    }
    __syncthreads();  // B

    // ---- layer 2 (same 8-chain schedule) ----
    float h2_0, h2_1, h2_2, h2_3;
    {
      f16x8 av0 = *(const f16x8*)(hp1 + 0 * 64);
      f16x8 av1 = *(const f16x8*)(hp1 + 1 * 64);
      f16x8 av2 = *(const f16x8*)(hp1 + 2 * 64);
      f16x8 av3 = *(const f16x8*)(hp1 + 3 * 64);
      f16x8 av4 = *(const f16x8*)(hp1 + 4 * 64);
      f16x8 av5 = *(const f16x8*)(hp1 + 5 * 64);
      f16x8 av6 = *(const f16x8*)(hp1 + 6 * 64);
      f16x8 av7 = *(const f16x8*)(hp1 + 7 * 64);
      f32x4 d0a = {0.f, 0.f, 0.f, 0.f}, d1a = {0.f, 0.f, 0.f, 0.f};
      f32x4 d2a = {0.f, 0.f, 0.f, 0.f}, d3a = {0.f, 0.f, 0.f, 0.f};
      f32x4 d0b = {0.f, 0.f, 0.f, 0.f}, d1b = {0.f, 0.f, 0.f, 0.f};
      f32x4 d2b = {0.f, 0.f, 0.f, 0.f}, d3b = {0.f, 0.f, 0.f, 0.f};
      asm volatile("s_nop 1"
                   : "+v"(d0a), "+v"(d1a), "+v"(d2a), "+v"(d3a),
                     "+v"(d0b), "+v"(d1b), "+v"(d2b), "+v"(d3b));
      M4(a, av0, 2, 0) M4(b, av4, 2, 4)
      M4(a, av1, 2, 1) M4(b, av5, 2, 5)
      M4(a, av2, 2, 2) M4(b, av6, 2, 6)
      M4(a, av3, 2, 3) M4(b, av7, 2, 7)
      asm volatile("s_nop 7\n\ts_nop 7"
                   : "+v"(d0a), "+v"(d1a), "+v"(d2a), "+v"(d3a),
                     "+v"(d0b), "+v"(d1b), "+v"(d2b), "+v"(d3b));
      h2_0 = xtanh((d0a[0] + d0b[0]) * WDESCALE + b2_0);
      h2_1 = xtanh((d1a[0] + d1b[0]) * WDESCALE + b2_1);
      h2_2 = xtanh((d2a[0] + d2b[0]) * WDESCALE + b2_2);
      h2_3 = xtanh((d3a[0] + d3b[0]) * WDESCALE + b2_3);
    }

    // ---- output layer: per-lane partials over 4 j's, DPP row all-reduce ----
    float p0 = h2_0 * wo0_0 + h2_1 * wo0_1 + h2_2 * wo0_2 + h2_3 * wo0_3;
    float p1 = h2_0 * wo1_0 + h2_1 * wo1_1 + h2_2 * wo1_2 + h2_3 * wo1_3;
    float p2 = h2_0 * wo2_0 + h2_1 * wo2_1 + h2_2 * wo2_2 + h2_3 * wo2_3;
    float p3 = h2_0 * wo3_0 + h2_1 * wo3_1 + h2_2 * wo3_2 + h2_3 * wo3_3;
    float p4 = h2_0 * wo4_0 + h2_1 * wo4_1 + h2_2 * wo4_2 + h2_3 * wo4_3;
    DPPADD(p0, 0x121) DPPADD(p0, 0x122) DPPADD(p0, 0x124) DPPADD(p0, 0x128)
    DPPADD(p1, 0x121) DPPADD(p1, 0x122) DPPADD(p1, 0x124) DPPADD(p1, 0x128)
    DPPADD(p2, 0x121) DPPADD(p2, 0x122) DPPADD(p2, 0x124) DPPADD(p2, 0x128)
    DPPADD(p3, 0x121) DPPADD(p3, 0x122) DPPADD(p3, 0x124) DPPADD(p3, 0x128)
    DPPADD(p4, 0x121) DPPADD(p4, 0x122) DPPADD(p4, 0x124) DPPADD(p4, 0x128)
    // every lane now holds the wave's 64-j sums; lane m (<5) writes slot m*4+w
    float pv = lane == 0 ? p0 : lane == 1 ? p1 : lane == 2 ? p2
                                          : lane == 3 ? p3 : p4;
    if (lane < 5) sWP[lane * 4 + w] = pv;
    __syncthreads();  // C

    // ---- finalize on ALL threads: quad-xor reduce over w, transforms ----
    float v = sWP[lane];  // lane l: m = l>>2, w = l&3 (slots >=20 are 0)
    DPPADD(v, 0xB1)       // quad_perm xor1
    DPPADD(v, 0x4E)       // quad_perm xor2 -> all 4 lanes of quad m hold o_m
    float o0 = RDLANE(v, 0) + bo0;
    float o1 = RDLANE(v, 4) + bo1;
    float o2 = RDLANE(v, 8) + bo2;
    float o3 = RDLANE(v, 12) + bo3;
    float o4 = RDLANE(v, 16) + bo4;
    if (tid == 0) {
      gout[t] = o4;           // q_output[t] = raw mlp output m=4 at state_t
      gout[TT + t] = s0;      // s_snow_nn[t] (pre-update)
      gout[2 * TT + t] = s1;  // s_water_nn[t]
    }
    float sh0 = xsinh(o0), sh1 = xsinh(o1), sh2 = xsinh(o2);
    float e3x = xexp(o3), e4x = xexp(o4);
    float stn = xstep(-tm), st0 = xstep(s0), st1 = xstep(s1);
    float psn = fmaxf(sh0 * stn, 0.0f);
    float prn = fmaxf(sh1, 0.0f);
    float mm = fmaxf(st0 * sh2, 0.0f);
    float evt = st1 * e3x * ld;
    float qq = st1 * e4x;
    s0 += psn - mm;                 // DT = 1
    s1 += prn + mm - evt - qq;
    Fc = Fn;
  }
#undef M4
#undef MFMAV
}

extern "C" void kernel_launch(void* const* d_in, const int* in_sizes, int n_in,
                              void* d_out, int out_size, void* d_ws, size_t ws_size,
                              hipStream_t stream) {
  const float* gin   = (const float*)d_in[0];
  const float* gdayl = (const float*)d_in[1];
  const float* gW0   = (const float*)d_in[2];
  const float* gb0   = (const float*)d_in[3];
  const float* gW1   = (const float*)d_in[4];
  const float* gb1   = (const float*)d_in[5];
  const float* gW2   = (const float*)d_in[6];
  const float* gb2   = (const float*)d_in[7];
  const float* gWout = (const float*)d_in[8];
  const float* gbout = (const float*)d_in[9];
  float* gout = (float*)d_out;
  exphydro_scan<<<dim3(1), dim3(256), 0, stream>>>(
      gin, gdayl, gW0, gb0, gW1, gb1, gW2, gb2, gWout, gbout, gout);
}

// Round 14
// 4828.529 us; speedup vs baseline: 1.1675x; 1.1675x over previous
//
#include <hip/hip_runtime.h>
#include <hip/hip_bf16.h>

#define TT 3650
#define HH 256

typedef _Float16 f16x4 __attribute__((ext_vector_type(4)));
typedef _Float16 f16x8 __attribute__((ext_vector_type(8)));
typedef float f32x4 __attribute__((ext_vector_type(4)));

__device__ __forceinline__ float xexp2(float x) { return __builtin_amdgcn_exp2f(x); }
__device__ __forceinline__ float xrcp(float x) { return __builtin_amdgcn_rcpf(x); }
__device__ __forceinline__ float xexp(float x) { return xexp2(x * 1.4426950408889634f); }
__device__ __forceinline__ float xtanh(float x) {
  float e = xexp2(x * 2.8853900817779268f);  // e^{2x}
  return 1.0f - 2.0f * xrcp(e + 1.0f);
}
__device__ __forceinline__ float xstep(float x) {  // sigmoid(10x)
  return xrcp(1.0f + xexp2(-14.426950408889634f * x));
}
__device__ __forceinline__ float xsinh(float x) {
  float e = xexp(x);
  return 0.5f * (e - xrcp(e));
}

#define DPPADD(x, ctrl)                                                        \
  (x) += __builtin_bit_cast(float, __builtin_amdgcn_update_dpp(                \
            0, __builtin_bit_cast(int, (x)), (ctrl), 0xf, 0xf, false));
#define RDLANE(x, l)                                                           \
  __builtin_bit_cast(float,                                                    \
      __builtin_amdgcn_readlane(__builtin_bit_cast(int, (x)), (l)))

#define REP8(M) M(0) M(1) M(2) M(3) M(4) M(5) M(6) M(7)
#define REPC(M) M(0) M(1) M(2) M(3)

// Weights stored as fp16 of (W * 2^10): avoids fp16-denormal weights, which
// the MFMA pipe flushes (round-9 drift). Descale folded into the post-MFMA FMA.
#define WSCALE 1024.0f
#define WDESCALE 0.0009765625f

#define SF_PAD 2

__global__ void __launch_bounds__(256, 1) exphydro_scan(
    const float* __restrict__ gin, const float* __restrict__ gdayl,
    const float* __restrict__ gW0, const float* __restrict__ gb0,
    const float* __restrict__ gW1, const float* __restrict__ gb1,
    const float* __restrict__ gW2, const float* __restrict__ gb2,
    const float* __restrict__ gWout, const float* __restrict__ gbout,
    float* __restrict__ gout) {
  __shared__ alignas(16) _Float16 h0l[HH];   // 512 B activation buffers
  __shared__ alignas(16) _Float16 h1l[HH];
  __shared__ float sWP[64];                  // [m][w]: slot m*4+w, 20 used
  __shared__ f32x4 sF[TT + SF_PAD];          // packed forcings {p,tm,ld,0}
  // Output buffers in LDS: keeps global stores (and thus vmcnt(0) drains at
  // every __syncthreads) OFF the per-step critical path. Flushed after loop.
  // Total LDS ~103.5 KB -> still only 1 block/CU.
  __shared__ float sQ[TT], sS0[TT], sS1[TT];

  const int tid = threadIdx.x;
  const int lane = tid & 63;
  const int w = tid >> 6;          // wave 0..3
  const int li = lane & 15;        // MFMA col within tile
  const int g = lane >> 4;         // k-group 0..3
  const int jb = 64 * w + 4 * li;  // this lane's 4 consecutive j's: jb+0..3

  // ---- stage packed forcings ----
  for (int i = tid; i < TT; i += 256) {
    f32x4 F = {gin[5 * i + 2], gin[5 * i + 3], gdayl[i], 0.0f};
    sF[i] = F;
  }
  if (tid < 2 * SF_PAD) {  // make the t+1 prefetch at t=TT-1 read defined data
    f32x4 Z = {0.f, 0.f, 0.f, 0.f};
    sF[TT + tid - ((tid < SF_PAD) ? 0 : SF_PAD)] = Z;  // sF[TT..TT+SF_PAD)
  }
  if (tid < 64) sWP[tid] = 0.0f;   // slots >=20 stay 0 forever

  // ---- per-thread constants (j = jb + c, c = 0..3) ----
  float s0 = gin[0], s1 = gin[1];
  const float bo0 = gbout[0], bo1 = gbout[1], bo2 = gbout[2], bo3 = gbout[3],
              bo4 = gbout[4];
#define CDECL(c)                                                               \
  const float w00_##c = gW0[jb + (c)], w01_##c = gW0[HH + jb + (c)],           \
              w02_##c = gW0[2 * HH + jb + (c)],                                \
              w03_##c = gW0[3 * HH + jb + (c)], b0_##c = gb0[jb + (c)],        \
              b1_##c = gb1[jb + (c)], b2_##c = gb2[jb + (c)],                  \
              wo0_##c = gWout[5 * (jb + (c)) + 0],                             \
              wo1_##c = gWout[5 * (jb + (c)) + 1],                             \
              wo2_##c = gWout[5 * (jb + (c)) + 2],                             \
              wo3_##c = gWout[5 * (jb + (c)) + 3],                             \
              wo4_##c = gWout[5 * (jb + (c)) + 4];
  REPC(CDECL)
#undef CDECL

  // ---- weight B-fragments -> AGPRs (native MFMA operands, r10-proven).
  // Fragment (layer L, chain c, slice i): lane holds B[k][col=li] with
  // k = 32i + 8g + e, column j = jb + c.
#define FDECL(i) f16x8 a1_0_##i, a1_1_##i, a1_2_##i, a1_3_##i,                 \
                       a2_0_##i, a2_1_##i, a2_2_##i, a2_3_##i;
  REP8(FDECL)
#undef FDECL
#define MK(dst, G, i, c)                                                       \
  {                                                                            \
    const float* p = (G) + (32 * (i) + g * 8) * HH + jb + (c);                 \
    f16x8 f;                                                                   \
    f[0] = (_Float16)(p[0] * WSCALE);      f[1] = (_Float16)(p[HH] * WSCALE);  \
    f[2] = (_Float16)(p[2 * HH] * WSCALE); f[3] = (_Float16)(p[3 * HH] * WSCALE); \
    f[4] = (_Float16)(p[4 * HH] * WSCALE); f[5] = (_Float16)(p[5 * HH] * WSCALE); \
    f[6] = (_Float16)(p[6 * HH] * WSCALE); f[7] = (_Float16)(p[7 * HH] * WSCALE); \
    dst = f;                                                                   \
    asm volatile("" : "+a"(dst));                                              \
  }
#define FINIT(i)                                                               \
  MK(a1_0_##i, gW1, i, 0) MK(a1_1_##i, gW1, i, 1)                              \
  MK(a1_2_##i, gW1, i, 2) MK(a1_3_##i, gW1, i, 3)                              \
  MK(a2_0_##i, gW2, i, 0) MK(a2_1_##i, gW2, i, 1)                              \
  MK(a2_2_##i, gW2, i, 2) MK(a2_3_##i, gW2, i, 3)
  REP8(FINIT)
#undef FINIT
#undef MK

  const char* hp0 = (const char*)h0l + g * 16;  // A-fill base (k-group window)
  const char* hp1 = (const char*)h1l + g * 16;

  // Non-volatile MFMA (r12-proven best): the compiler interleaves ds_reads
  // and MFMAs better than any source-pinned order (r13 regression evidence).
#define MFMA(acc, a, b)                                                        \
  asm("v_mfma_f32_16x16x32_f16 %0, %1, %2, %0" : "+v"(acc) : "v"(a), "a"(b));

  __syncthreads();  // staging + sWP zero visible

  f32x4 Fc = sF[0];
  for (int t = 0; t < TT; ++t) {
    const float p_in = Fc[0];
    const float tm = Fc[1];
    const float ld = Fc[2];

    // ---- layer 0 (VALU; each lane computes its 4 j's, g>0 redundant) ----
#define L0C(c)                                                                 \
  float h0_##c =                                                               \
      xtanh(b0_##c + s0 * w00_##c + s1 * w01_##c + p_in * w02_##c + tm * w03_##c);
    REPC(L0C)
#undef L0C
    if (lane < 16) {
      f16x4 hv = {(_Float16)h0_0, (_Float16)h0_1, (_Float16)h0_2,
                  (_Float16)h0_3};
      *(f16x4*)((char*)h0l + (jb << 1)) = hv;  // one ds_write_b64
    }
    __syncthreads();  // A

    f32x4 Fn = sF[t + 1];  // prefetch next forcings; hides under layer-1 MFMAs

    // ---- layer 1: 32 MFMA on 4 independent chains (one per j-subcolumn c);
    // the same av feeds all 4 chains, so DS reads stay at 8/wave ----
    f32x4 d0 = {0.f, 0.f, 0.f, 0.f}, d1 = {0.f, 0.f, 0.f, 0.f};
    f32x4 d2 = {0.f, 0.f, 0.f, 0.f}, d3 = {0.f, 0.f, 0.f, 0.f};
    asm volatile("s_nop 1" : "+v"(d0), "+v"(d1), "+v"(d2), "+v"(d3));
#define MM1(i)                                                                 \
  {                                                                            \
    f16x8 av = *(const f16x8*)(hp0 + (i) * 64);                                \
    MFMA(d0, av, a1_0_##i) MFMA(d1, av, a1_1_##i)                              \
    MFMA(d2, av, a1_2_##i) MFMA(d3, av, a1_3_##i)                              \
  }
    REP8(MM1)
#undef MM1
    asm volatile("s_nop 7\n\ts_nop 7" : "+v"(d0), "+v"(d1), "+v"(d2), "+v"(d3));
#define H1C(c) float h1_##c = xtanh(d##c[0] * WDESCALE + b1_##c);
    REPC(H1C)
#undef H1C
    if (lane < 16) {
      f16x4 hv = {(_Float16)h1_0, (_Float16)h1_1, (_Float16)h1_2,
                  (_Float16)h1_3};
      *(f16x4*)((char*)h1l + (jb << 1)) = hv;
    }
    __syncthreads();  // B

    // ---- layer 2 (same schedule) ----
    f32x4 e0 = {0.f, 0.f, 0.f, 0.f}, e1 = {0.f, 0.f, 0.f, 0.f};
    f32x4 e2 = {0.f, 0.f, 0.f, 0.f}, e3 = {0.f, 0.f, 0.f, 0.f};
    asm volatile("s_nop 1" : "+v"(e0), "+v"(e1), "+v"(e2), "+v"(e3));
#define MM2(i)                                                                 \
  {                                                                            \
    f16x8 av = *(const f16x8*)(hp1 + (i) * 64);                                \
    MFMA(e0, av, a2_0_##i) MFMA(e1, av, a2_1_##i)                              \
    MFMA(e2, av, a2_2_##i) MFMA(e3, av, a2_3_##i)                              \
  }
    REP8(MM2)
#undef MM2
    asm volatile("s_nop 7\n\ts_nop 7" : "+v"(e0), "+v"(e1), "+v"(e2), "+v"(e3));
#define H2C(c) float h2_##c = xtanh(e##c[0] * WDESCALE + b2_##c);
    REPC(H2C)
#undef H2C

    // ---- output layer: per-lane partials over 4 j's, DPP row all-reduce ----
    float p0 = h2_0 * wo0_0 + h2_1 * wo0_1 + h2_2 * wo0_2 + h2_3 * wo0_3;
    float p1 = h2_0 * wo1_0 + h2_1 * wo1_1 + h2_2 * wo1_2 + h2_3 * wo1_3;
    float p2 = h2_0 * wo2_0 + h2_1 * wo2_1 + h2_2 * wo2_2 + h2_3 * wo2_3;
    float p3 = h2_0 * wo3_0 + h2_1 * wo3_1 + h2_2 * wo3_2 + h2_3 * wo3_3;
    float p4 = h2_0 * wo4_0 + h2_1 * wo4_1 + h2_2 * wo4_2 + h2_3 * wo4_3;
    DPPADD(p0, 0x121) DPPADD(p0, 0x122) DPPADD(p0, 0x124) DPPADD(p0, 0x128)
    DPPADD(p1, 0x121) DPPADD(p1, 0x122) DPPADD(p1, 0x124) DPPADD(p1, 0x128)
    DPPADD(p2, 0x121) DPPADD(p2, 0x122) DPPADD(p2, 0x124) DPPADD(p2, 0x128)
    DPPADD(p3, 0x121) DPPADD(p3, 0x122) DPPADD(p3, 0x124) DPPADD(p3, 0x128)
    DPPADD(p4, 0x121) DPPADD(p4, 0x122) DPPADD(p4, 0x124) DPPADD(p4, 0x128)
    // every lane now holds the wave's 64-j sums; lane m (<5) writes slot m*4+w
    float pv = lane == 0 ? p0 : lane == 1 ? p1 : lane == 2 ? p2
                                          : lane == 3 ? p3 : p4;
    if (lane < 5) sWP[lane * 4 + w] = pv;
    __syncthreads();  // C

    // ---- finalize on ALL threads: quad-xor reduce over w, transforms ----
    float v = sWP[lane];  // lane l: m = l>>2, w = l&3 (slots >=20 are 0)
    DPPADD(v, 0xB1)       // quad_perm xor1
    DPPADD(v, 0x4E)       // quad_perm xor2 -> all 4 lanes of quad m hold o_m
    float o0 = RDLANE(v, 0) + bo0;
    float o1 = RDLANE(v, 4) + bo1;
    float o2 = RDLANE(v, 8) + bo2;
    float o3 = RDLANE(v, 12) + bo3;
    float o4 = RDLANE(v, 16) + bo4;
    if (tid == 64) {  // wave 1 buffers outputs in LDS (wave 0 owns sWP writes)
      sQ[t] = o4;           // q_output[t] = raw mlp output m=4 at state_t
      sS0[t] = s0;          // s_snow_nn[t] (pre-update)
      sS1[t] = s1;          // s_water_nn[t]
    }
    float sh0 = xsinh(o0), sh1 = xsinh(o1), sh2 = xsinh(o2);
    float e3x = xexp(o3), e4x = xexp(o4);
    float stn = xstep(-tm), st0 = xstep(s0), st1 = xstep(s1);
    float psn = fmaxf(sh0 * stn, 0.0f);
    float prn = fmaxf(sh1, 0.0f);
    float mm = fmaxf(st0 * sh2, 0.0f);
    float evt = st1 * e3x * ld;
    float qq = st1 * e4x;
    s0 += psn - mm;                 // DT = 1
    s1 += prn + mm - evt - qq;
    Fc = Fn;
  }
#undef MFMA

  // ---- flush buffered outputs to global (coalesced) ----
  __syncthreads();
  for (int i = tid; i < TT; i += 256) {
    gout[i] = sQ[i];
    gout[TT + i] = sS0[i];
    gout[2 * TT + i] = sS1[i];
  }
}

extern "C" void kernel_launch(void* const* d_in, const int* in_sizes, int n_in,
                              void* d_out, int out_size, void* d_ws, size_t ws_size,
                              hipStream_t stream) {
  const float* gin   = (const float*)d_in[0];
  const float* gdayl = (const float*)d_in[1];
  const float* gW0   = (const float*)d_in[2];
  const float* gb0   = (const float*)d_in[3];
  const float* gW1   = (const float*)d_in[4];
  const float* gb1   = (const float*)d_in[5];
  const float* gW2   = (const float*)d_in[6];
  const float* gb2   = (const float*)d_in[7];
  const float* gWout = (const float*)d_in[8];
  const float* gbout = (const float*)d_in[9];
  float* gout = (float*)d_out;
  exphydro_scan<<<dim3(1), dim3(256), 0, stream>>>(
      gin, gdayl, gW0, gb0, gW1, gb1, gW2, gb2, gWout, gbout, gout);
}